// Round 9
// baseline (760.422 us; speedup 1.0000x reference)
//
#include <hip/hip_runtime.h>

// EmbeddingLSQ: out[t,d] = (idx[t]==0) ? 0 : rint(clamp(W[d,idx[t]]/a,-8,7))*a
// idx[t] = position of the 1.0 in one-hot row x[t,:].
//
// DISCRIMINATING EXPERIMENT (R9): no early exit. Kernel 1 is a dense
// grid-stride streaming scan of the FULL 524 MB of x — identical access
// pattern to the harness fill kernels that measurably run at 6.4 TB/s
// (no data-dependent branch in the address stream, no per-wave serial
// window chain). On the (one per row) nonzero hit it writes idx[t] to d_ws.
// Kernel 2: wave-per-token gather of w column + fp32 LSQ quant + coalesced
// stores (unchanged from R4, measured ~30 us).
//
// Forked prediction: if the old ballot scan was latency-capped (~150 us),
// dur drops to ~660; if it was already aggregate-BW-bound (~42 us), dur
// rises to ~760 and the R4 kernel was at the floor.

typedef float        v4f __attribute__((ext_vector_type(4)));
typedef unsigned int v4u __attribute__((ext_vector_type(4)));
typedef unsigned int u32;

constexpr int VOCAB  = 32000;
constexpr int DIM    = 1024;
constexpr int TOKENS = 4096;
constexpr int V4     = VOCAB / 4;          // 8000 16B chunks per x row
constexpr u32 NCHUNK = (u32)TOKENS * V4;   // 32,768,000 chunks total
constexpr int SBLK   = 2560;               // scan blocks (10/CU)
constexpr int STHR   = 256;
constexpr u32 STRIDE = (u32)SBLK * STHR;   // 655,360 threads
constexpr int KPT    = NCHUNK / STRIDE;    // 50 chunks per thread (exact)

__device__ __forceinline__ u32 nz(v4u c) { return c.x | c.y | c.z | c.w; }
__device__ __forceinline__ int word_of(v4u c) {
    return c.x ? 0 : (c.y ? 1 : (c.z ? 2 : 3));
}

// ---- Kernel 1: dense streaming scan of all of x ----
__global__ __launch_bounds__(STHR) void scan_all_kernel(
    const float* __restrict__ x, int* __restrict__ idxs)
{
    const u32 gid = blockIdx.x * STHR + threadIdx.x;
    const v4u* xp = reinterpret_cast<const v4u*>(x);

    #pragma unroll
    for (int k0 = 0; k0 < KPT; k0 += 5) {
        // 5 independent 16B loads in flight, then 5 cheap checks (rare hit)
        v4u c0 = __builtin_nontemporal_load(&xp[gid + (u32)(k0 + 0) * STRIDE]);
        v4u c1 = __builtin_nontemporal_load(&xp[gid + (u32)(k0 + 1) * STRIDE]);
        v4u c2 = __builtin_nontemporal_load(&xp[gid + (u32)(k0 + 2) * STRIDE]);
        v4u c3 = __builtin_nontemporal_load(&xp[gid + (u32)(k0 + 3) * STRIDE]);
        v4u c4 = __builtin_nontemporal_load(&xp[gid + (u32)(k0 + 4) * STRIDE]);
        u32 h0 = nz(c0), h1 = nz(c1), h2 = nz(c2), h3 = nz(c3), h4 = nz(c4);
        if (h0 | h1 | h2 | h3 | h4) {          // 4096 hits / 32.8M chunks
            #pragma unroll
            for (int j = 0; j < 5; ++j) {
                v4u c = j == 0 ? c0 : j == 1 ? c1 : j == 2 ? c2 : j == 3 ? c3 : c4;
                if (nz(c)) {
                    const u32 flat = gid + (u32)(k0 + j) * STRIDE;
                    const u32 t    = flat / (u32)V4;       // magic-mul div
                    const u32 cir  = flat - t * (u32)V4;   // chunk in row
                    idxs[t] = 4 * (int)cir + word_of(c);
                }
            }
        }
    }
}

// ---- Kernel 2: wave per token — gather w column, quant, store ----
__global__ __launch_bounds__(64) void gather_kernel(
    const float* __restrict__ w,
    const float* __restrict__ alpha,
    const int* __restrict__ idxs,
    float* __restrict__ out)
{
    const int t    = blockIdx.x;
    const int lane = threadIdx.x;
    const int idx  = idxs[t];                  // uniform -> scalar load

    v4f* orow = reinterpret_cast<v4f*>(out + (size_t)t * DIM);
    if (idx <= 0) {                            // PAD_IDX -> zero row
        v4f z = 0.f;
        #pragma unroll
        for (int j = 0; j < 4; ++j) orow[lane + 64 * j] = z;
    } else {
        const float a = alpha[0];
        const size_t col = (size_t)idx;
        float wv[16];
        #pragma unroll
        for (int j = 0; j < 4; ++j) {          // 16 independent gathers
            const int d0 = 4 * lane + 256 * j;
            wv[4*j+0] = w[(size_t)(d0 + 0) * VOCAB + col];
            wv[4*j+1] = w[(size_t)(d0 + 1) * VOCAB + col];
            wv[4*j+2] = w[(size_t)(d0 + 2) * VOCAB + col];
            wv[4*j+3] = w[(size_t)(d0 + 3) * VOCAB + col];
        }
        #pragma unroll
        for (int j = 0; j < 4; ++j) {
            v4f q;
            q.x = rintf(fminf(fmaxf(wv[4*j+0] / a, -8.f), 7.f)) * a;
            q.y = rintf(fminf(fmaxf(wv[4*j+1] / a, -8.f), 7.f)) * a;
            q.z = rintf(fminf(fmaxf(wv[4*j+2] / a, -8.f), 7.f)) * a;
            q.w = rintf(fminf(fmaxf(wv[4*j+3] / a, -8.f), 7.f)) * a;
            orow[lane + 64 * j] = q;           // 1 KB coalesced store/instr
        }
    }
}

extern "C" void kernel_launch(void* const* d_in, const int* in_sizes, int n_in,
                              void* d_out, int out_size, void* d_ws, size_t ws_size,
                              hipStream_t stream) {
    const float* x     = (const float*)d_in[0];   // [TOKENS, VOCAB]
    const float* w     = (const float*)d_in[1];   // [DIM, VOCAB]
    const float* alpha = (const float*)d_in[2];   // [1]
    float* out         = (float*)d_out;           // [TOKENS, DIM]
    int*   idxs        = (int*)d_ws;              // 16 KB scratch
    // every row of one-hot x has exactly one nonzero, so all 4096 idxs are
    // written by scan_all_kernel each launch (ws poison is overwritten).

    scan_all_kernel<<<SBLK, STHR, 0, stream>>>(x, idxs);
    gather_kernel<<<TOKENS, 64, 0, stream>>>(w, alpha, idxs, out);
}